// Round 7
// baseline (665.460 us; speedup 1.0000x reference)
//
#include <hip/hip_runtime.h>
#include <math.h>

// ---------------------------------------------------------------------------
// GCN 3-layer forward. Round 6: L3-pollution fix for the aggregation.
// Theory: agg's 51 MB fp32 h-write stream evicted the 25.6 MB packed-P gather
// target from L3 (FETCH 193 MB >> 40 MB honest traffic). Changes:
//   - non-temporal stores for h, non-temporal loads for the ep edge stream
//   - h stored packed bf162 (halves h write + next-GEMM read)
//   - 8-deep named-scalar gather unroll (VGPR headroom: 24 -> ~40)
// CSR build (round-5 chunk-claimed bucket partition) unchanged.
// ---------------------------------------------------------------------------

#define CHUNK 8192  // edges per partition chunk (256 thr x 32)

__device__ __forceinline__ float2 bf2_unpack(unsigned u) {
    float2 r;
    r.x = __uint_as_float(u << 16);
    r.y = __uint_as_float(u & 0xffff0000u);
    return r;
}
__device__ __forceinline__ unsigned bf2_pack(float a, float b) {
    unsigned ua = __float_as_uint(a);
    unsigned ub = __float_as_uint(b);
    ua = (ua + 0x7fffu + ((ua >> 16) & 1u)) >> 16;
    ub = (ub + 0x7fffu + ((ub >> 16) & 1u)) >> 16;
    return ua | (ub << 16);
}

// ---------- edge-index dtype detection (int32 vs int64 layout) ----------
__global__ void k_detect(const unsigned* __restrict__ raw, int nsample, int* __restrict__ flag) {
    int i = blockIdx.x * blockDim.x + threadIdx.x;
    if (i < nsample) {
        if (raw[2 * i + 1] != 0u) atomicOr(flag, 1);
    }
}

__device__ __forceinline__ int edge_src(const unsigned* raw, int e, int E, int is64) {
    return is64 ? (int)raw[2 * (size_t)e] : (int)raw[e];
}
__device__ __forceinline__ int edge_dst(const unsigned* raw, int e, int E, int is64) {
    return is64 ? (int)raw[2 * ((size_t)E + e)] : (int)raw[(size_t)E + e];
}

// ---------- per-chunk bucket histograms + merged totals ----------
__global__ __launch_bounds__(256) void k_bhist(const unsigned* __restrict__ raw,
                                               int* __restrict__ bhist, int* __restrict__ chist,
                                               const int* __restrict__ flag,
                                               int E, int NB, int nchunks) {
    __shared__ int h[512];
    int is64 = (*flag == 0);
    for (int c = blockIdx.x; c < nchunks; c += gridDim.x) {
        for (int t = threadIdx.x; t < 512; t += 256) h[t] = 0;
        __syncthreads();
        int base = c * CHUNK;
        int end = (base + CHUNK < E) ? base + CHUNK : E;
        for (int e = base + threadIdx.x; e < end; e += 256) {
            int d = edge_dst(raw, e, E, is64);
            atomicAdd(&h[d >> 8], 1);
        }
        __syncthreads();
        for (int t = threadIdx.x; t < NB; t += 256) {
            int v = h[t];
            chist[(size_t)c * 512 + t] = v;
            if (v) atomicAdd(&bhist[t], v);
        }
        __syncthreads();
    }
}

// ---------- exclusive scan over buckets -> bases + cursors ----------
__global__ __launch_bounds__(512) void k_bscan(const int* __restrict__ bhist,
                                               int* __restrict__ bstart,
                                               int* __restrict__ bcur, int NB) {
    __shared__ int s[512];
    int tid = threadIdx.x;
    int v = (tid < NB) ? bhist[tid] : 0;
    s[tid] = v;
    __syncthreads();
    for (int off = 1; off < 512; off <<= 1) {
        int t = (tid >= off) ? s[tid - off] : 0;
        __syncthreads();
        if (tid >= off) s[tid] += t;
        __syncthreads();
    }
    int ex = s[tid] - v;  // exclusive
    if (tid <= NB) {
        int val = (tid < NB) ? ex : s[NB > 0 ? NB - 1 : 0];
        bstart[tid] = val;
        if (tid < NB) bcur[tid] = val;
    }
}

// ---------- partition: chunk-batched claims, LDS-cursor scatter ----------
// payload word0 = src | (dst&255)<<24  (requires N < 2^24; N=100k here)
__global__ __launch_bounds__(256) void k_part(const unsigned* __restrict__ raw,
                                              const float* __restrict__ ew,
                                              const int* __restrict__ chist,
                                              int* __restrict__ bcur, int2* __restrict__ staging,
                                              const int* __restrict__ flag,
                                              int E, int NB, int nchunks) {
    __shared__ int cur[512];
    int is64 = (*flag == 0);
    for (int c = blockIdx.x; c < nchunks; c += gridDim.x) {
        for (int t = threadIdx.x; t < NB; t += 256) {
            int v = chist[(size_t)c * 512 + t];
            cur[t] = v ? atomicAdd(&bcur[t], v) : 0;
        }
        __syncthreads();
        int base = c * CHUNK;
        int end = (base + CHUNK < E) ? base + CHUNK : E;
        for (int e = base + threadIdx.x; e < end; e += 256) {
            int s = edge_src(raw, e, E, is64);
            int d = edge_dst(raw, e, E, is64);
            float w = ew[e];
            int pos = atomicAdd(&cur[d >> 8], 1);  // LDS atomic
            staging[pos] = make_int2(s | ((d & 255) << 24), __float_as_int(w));
        }
        __syncthreads();
    }
}

// ---------- per-bucket finalize: rowptr, dinv, local scatter -> ep ----------
__global__ __launch_bounds__(256) void k_bucket(const int* __restrict__ bstart,
                                                const int2* __restrict__ staging,
                                                int* __restrict__ rowptr, float* __restrict__ dinv,
                                                int2* __restrict__ ep, int N, int NB) {
    __shared__ int cnt[256];
    __shared__ float dw[256];
    __shared__ int sc[256];
    __shared__ int cur[256];

    const int b = blockIdx.x;
    const int t = threadIdx.x;
    const int n0 = b << 8;
    const int nn = (N - n0 < 256) ? (N - n0) : 256;
    const int es = bstart[b], ee = bstart[b + 1];

    cnt[t] = 0;
    dw[t] = 0.f;
    __syncthreads();

    for (int j = es + t; j < ee; j += 256) {
        int2 p = staging[j];
        int dl = ((unsigned)p.x) >> 24;
        atomicAdd(&cnt[dl], 1);
        atomicAdd(&dw[dl], __int_as_float(p.y));
    }
    __syncthreads();

    int v = cnt[t];
    sc[t] = v;
    __syncthreads();
    for (int off = 1; off < 256; off <<= 1) {
        int tv = (t >= off) ? sc[t - off] : 0;
        __syncthreads();
        if (t >= off) sc[t] += tv;
        __syncthreads();
    }
    int exoff = sc[t] - v;
    cur[t] = es + exoff;
    if (t < nn) {
        rowptr[n0 + t] = es + exoff;
        dinv[n0 + t] = rsqrtf(dw[t] + 1.0f);  // deg includes self-loop 1.0
    }
    if (t == 0) rowptr[(n0 + 256 < N) ? (n0 + 256) : N] = ee;
    __syncthreads();

    for (int j = es + t; j < ee; j += 256) {
        int2 p = staging[j];
        int dl = ((unsigned)p.x) >> 24;
        int pos = atomicAdd(&cur[dl], 1);
        ep[pos] = make_int2(p.x & 0x00ffffff, p.y);
    }
}

// ---------- GEMM: Yp = pack_bf162( dinv[r] * act(X)[N,128] @ W ) ----------
// BN=false: X is fp32 [N,128].  BN=true: Xp is packed bf162 [N,64]; apply
// y = relu(x*scale+shift) while unpacking into LDS.
template <int DOUT, int KC, bool BN>
__global__ __launch_bounds__(256) void k_gemm(
    const float* __restrict__ X, const unsigned* __restrict__ Xp,
    const float* __restrict__ W,
    const float* __restrict__ scale, const float* __restrict__ shift,
    const float* __restrict__ dscale, unsigned* __restrict__ Y, int N)
{
    constexpr int NCH = 128 / KC;
    constexpr int NDW = DOUT / 2;
    __shared__ __align__(16) float Wl[KC * DOUT];
    __shared__ __align__(16) float Xs[4][8 * 128];
    __shared__ float sc_l[128], sh_l[128];

    const int tid = threadIdx.x;
    const int wave = tid >> 6, lane = tid & 63;
    if (BN) {
        if (tid < 128) { sc_l[tid] = scale[tid]; sh_l[tid] = shift[tid]; }
    }
    __syncthreads();

    const int srow = lane >> 3;
    const int skk = (lane & 7) * 16;  // 16 feats per staging lane

    for (int base = blockIdx.x * 32; base < N; base += gridDim.x * 32) {
        {
            int r = base + wave * 8 + srow;
            float vf[16];
            if (BN) {
                uint4 u0 = make_uint4(0, 0, 0, 0), u1 = u0;
                if (r < N) {
                    const uint4* p = (const uint4*)(Xp + (size_t)r * 64 + (lane & 7) * 8);
                    u0 = p[0]; u1 = p[1];
                }
                unsigned uu[8] = {u0.x, u0.y, u0.z, u0.w, u1.x, u1.y, u1.z, u1.w};
#pragma unroll
                for (int d = 0; d < 8; d++) {
                    float2 f = bf2_unpack(uu[d]);
                    vf[2 * d] = f.x;
                    vf[2 * d + 1] = f.y;
                }
#pragma unroll
                for (int j = 0; j < 16; j++)
                    vf[j] = fmaxf(vf[j] * sc_l[skk + j] + sh_l[skk + j], 0.f);
            } else {
                float4 v[4];
                if (r < N) {
                    const float4* p = (const float4*)(X + (size_t)r * 128 + skk);
                    v[0] = p[0]; v[1] = p[1]; v[2] = p[2]; v[3] = p[3];
                } else {
                    v[0] = v[1] = v[2] = v[3] = make_float4(0.f, 0.f, 0.f, 0.f);
                }
#pragma unroll
                for (int j = 0; j < 16; j++) vf[j] = ((const float*)v)[j];
            }
            float4* q = (float4*)&Xs[wave][srow * 128 + skk];
#pragma unroll
            for (int d = 0; d < 4; d++)
                q[d] = make_float4(vf[4 * d], vf[4 * d + 1], vf[4 * d + 2], vf[4 * d + 3]);
        }

        float acc0[8], acc1[8];
#pragma unroll
        for (int r = 0; r < 8; r++) { acc0[r] = 0.f; acc1[r] = 0.f; }

        for (int ch = 0; ch < NCH; ++ch) {
            __syncthreads();
            for (int idx = tid; idx < KC * DOUT / 4; idx += 256)
                ((float4*)Wl)[idx] = ((const float4*)(W + (size_t)ch * KC * DOUT))[idx];
            __syncthreads();

            for (int k = 0; k < KC; k += 4) {
                float4 a[8];
#pragma unroll
                for (int r = 0; r < 8; r++)
                    a[r] = *(const float4*)&Xs[wave][r * 128 + ch * KC + k];
#pragma unroll
                for (int kk = 0; kk < 4; kk++) {
                    float2 wv = make_float2(0.f, 0.f);
                    if (lane < NDW)
                        wv = *(const float2*)&Wl[(k + kk) * DOUT + 2 * lane];
#pragma unroll
                    for (int r = 0; r < 8; r++) {
                        float av = ((const float*)&a[r])[kk];
                        acc0[r] += av * wv.x;
                        acc1[r] += av * wv.y;
                    }
                }
            }
        }

#pragma unroll
        for (int r = 0; r < 8; r++) {
            int row = base + wave * 8 + r;
            if (row < N && lane < NDW) {
                float rs = dscale[row];
                Y[(size_t)row * NDW + lane] = bf2_pack(acc0[r] * rs, acc1[r] * rs);
            }
        }
    }
}

// ---------- aggregation (128-wide) -> packed bf16 h (nt) + BN partials ----------
__global__ __launch_bounds__(256) void k_agg128(
    const unsigned* __restrict__ xw, const int* __restrict__ rowptr,
    const unsigned long long* __restrict__ ep, const float* __restrict__ dinv,
    const float* __restrict__ bias, unsigned* __restrict__ h,
    float* __restrict__ bn_sum, float* __restrict__ bn_sq, int N)
{
    __shared__ float redS[512], redQ[512];
    const int lane = threadIdx.x & 63;
    const int wave = threadIdx.x >> 6;
    const int base = blockIdx.x * 64 + wave * 16;
    const float b0 = bias[2 * lane], b1 = bias[2 * lane + 1];
    float s0 = 0.f, s1 = 0.f, q0 = 0.f, q1 = 0.f;

    const int nmax = (N - base < 16) ? (N - base) : 16;
    for (int n = 0; n < nmax; n++) {
        const int i = base + n;
        const int rs = rowptr[i], re = rowptr[i + 1];
        const float di = dinv[i];
        float2 sv = bf2_unpack(xw[(size_t)i * 64 + lane]);
        float acc0 = sv.x, acc1 = sv.y;  // self-loop message xw'[i]
        int j = rs;
        for (; j + 8 <= re; j += 8) {
            unsigned long long u0 = __builtin_nontemporal_load(ep + j);
            unsigned long long u1 = __builtin_nontemporal_load(ep + j + 1);
            unsigned long long u2 = __builtin_nontemporal_load(ep + j + 2);
            unsigned long long u3 = __builtin_nontemporal_load(ep + j + 3);
            unsigned long long u4 = __builtin_nontemporal_load(ep + j + 4);
            unsigned long long u5 = __builtin_nontemporal_load(ep + j + 5);
            unsigned long long u6 = __builtin_nontemporal_load(ep + j + 6);
            unsigned long long u7 = __builtin_nontemporal_load(ep + j + 7);
            unsigned v0 = xw[(size_t)(unsigned)u0 * 64 + lane];
            unsigned v1 = xw[(size_t)(unsigned)u1 * 64 + lane];
            unsigned v2 = xw[(size_t)(unsigned)u2 * 64 + lane];
            unsigned v3 = xw[(size_t)(unsigned)u3 * 64 + lane];
            unsigned v4 = xw[(size_t)(unsigned)u4 * 64 + lane];
            unsigned v5 = xw[(size_t)(unsigned)u5 * 64 + lane];
            unsigned v6 = xw[(size_t)(unsigned)u6 * 64 + lane];
            unsigned v7 = xw[(size_t)(unsigned)u7 * 64 + lane];
            float c0 = __int_as_float((int)(u0 >> 32)), c1 = __int_as_float((int)(u1 >> 32));
            float c2 = __int_as_float((int)(u2 >> 32)), c3 = __int_as_float((int)(u3 >> 32));
            float c4 = __int_as_float((int)(u4 >> 32)), c5 = __int_as_float((int)(u5 >> 32));
            float c6 = __int_as_float((int)(u6 >> 32)), c7 = __int_as_float((int)(u7 >> 32));
            float2 f0 = bf2_unpack(v0), f1 = bf2_unpack(v1);
            float2 f2 = bf2_unpack(v2), f3 = bf2_unpack(v3);
            float2 f4 = bf2_unpack(v4), f5 = bf2_unpack(v5);
            float2 f6 = bf2_unpack(v6), f7 = bf2_unpack(v7);
            acc0 += c0 * f0.x + c1 * f1.x + c2 * f2.x + c3 * f3.x
                  + c4 * f4.x + c5 * f5.x + c6 * f6.x + c7 * f7.x;
            acc1 += c0 * f0.y + c1 * f1.y + c2 * f2.y + c3 * f3.y
                  + c4 * f4.y + c5 * f5.y + c6 * f6.y + c7 * f7.y;
        }
        for (; j + 4 <= re; j += 4) {
            unsigned long long u0 = __builtin_nontemporal_load(ep + j);
            unsigned long long u1 = __builtin_nontemporal_load(ep + j + 1);
            unsigned long long u2 = __builtin_nontemporal_load(ep + j + 2);
            unsigned long long u3 = __builtin_nontemporal_load(ep + j + 3);
            unsigned v0 = xw[(size_t)(unsigned)u0 * 64 + lane];
            unsigned v1 = xw[(size_t)(unsigned)u1 * 64 + lane];
            unsigned v2 = xw[(size_t)(unsigned)u2 * 64 + lane];
            unsigned v3 = xw[(size_t)(unsigned)u3 * 64 + lane];
            float c0 = __int_as_float((int)(u0 >> 32)), c1 = __int_as_float((int)(u1 >> 32));
            float c2 = __int_as_float((int)(u2 >> 32)), c3 = __int_as_float((int)(u3 >> 32));
            float2 f0 = bf2_unpack(v0), f1 = bf2_unpack(v1);
            float2 f2 = bf2_unpack(v2), f3 = bf2_unpack(v3);
            acc0 += c0 * f0.x + c1 * f1.x + c2 * f2.x + c3 * f3.x;
            acc1 += c0 * f0.y + c1 * f1.y + c2 * f2.y + c3 * f3.y;
        }
        for (; j < re; j++) {
            unsigned long long u = __builtin_nontemporal_load(ep + j);
            float c = __int_as_float((int)(u >> 32));
            float2 f = bf2_unpack(xw[(size_t)(unsigned)u * 64 + lane]);
            acc0 += c * f.x;
            acc1 += c * f.y;
        }
        acc0 = acc0 * di + b0;
        acc1 = acc1 * di + b1;
        __builtin_nontemporal_store(bf2_pack(acc0, acc1), &h[(size_t)i * 64 + lane]);
        s0 += acc0; s1 += acc1; q0 += acc0 * acc0; q1 += acc1 * acc1;
    }

    redS[wave * 128 + 2 * lane] = s0;
    redS[wave * 128 + 2 * lane + 1] = s1;
    redQ[wave * 128 + 2 * lane] = q0;
    redQ[wave * 128 + 2 * lane + 1] = q1;
    __syncthreads();
    if (threadIdx.x < 128) {
        int f = threadIdx.x;
        float ts = redS[f] + redS[128 + f] + redS[256 + f] + redS[384 + f];
        float tq = redQ[f] + redQ[128 + f] + redQ[256 + f] + redQ[384 + f];
        atomicAdd(&bn_sum[f], ts);
        atomicAdd(&bn_sq[f], tq);
    }
}

// ---------- BN finalize ----------
__global__ void k_bnfin(const float* __restrict__ bn_sum, const float* __restrict__ bn_sq,
                        const float* __restrict__ gamma, const float* __restrict__ beta,
                        float* __restrict__ scale, float* __restrict__ shift, int N) {
    int f = threadIdx.x;
    float inv = 1.0f / (float)N;
    float m = bn_sum[f] * inv;
    float v = bn_sq[f] * inv - m * m;
    float sc = gamma[f] * rsqrtf(v + 1e-5f);
    scale[f] = sc;
    shift[f] = beta[f] - m * sc;
}

// ---------- aggregation (40-wide, bf16 gather) + bias + log_softmax ----------
__global__ __launch_bounds__(256) void k_agg40(
    const unsigned* __restrict__ xw, const int* __restrict__ rowptr,
    const unsigned long long* __restrict__ ep, const float* __restrict__ dinv,
    const float* __restrict__ bias, float* __restrict__ out, int N)
{
    const int lane = threadIdx.x & 63;
    const int wave = threadIdx.x >> 6;
    const int half = lane >> 5;
    const int col = lane & 31;
    const bool act = col < 20;
    const int base = blockIdx.x * 64 + wave * 16;
    if (base >= N) return;
    const int cc = act ? col : 0;
    const float b0 = act ? bias[2 * col] : 0.f;
    const float b1 = act ? bias[2 * col + 1] : 0.f;

    for (int n = 0; n < 16; n += 2) {
        const int i = base + n + half;
        const bool valid = i < N;
        const int ic = valid ? i : 0;
        const int rs = rowptr[ic];
        int re = rowptr[ic + 1];
        re = valid ? re : rs;
        const float di = dinv[ic];
        float2 sv = bf2_unpack(xw[(size_t)ic * 20 + cc]);
        float acc0 = sv.x, acc1 = sv.y;  // self-loop message
        int j = rs;
        for (; j + 8 <= re; j += 8) {
            unsigned long long u0 = __builtin_nontemporal_load(ep + j);
            unsigned long long u1 = __builtin_nontemporal_load(ep + j + 1);
            unsigned long long u2 = __builtin_nontemporal_load(ep + j + 2);
            unsigned long long u3 = __builtin_nontemporal_load(ep + j + 3);
            unsigned long long u4 = __builtin_nontemporal_load(ep + j + 4);
            unsigned long long u5 = __builtin_nontemporal_load(ep + j + 5);
            unsigned long long u6 = __builtin_nontemporal_load(ep + j + 6);
            unsigned long long u7 = __builtin_nontemporal_load(ep + j + 7);
            unsigned v0 = xw[(size_t)(unsigned)u0 * 20 + cc];
            unsigned v1 = xw[(size_t)(unsigned)u1 * 20 + cc];
            unsigned v2 = xw[(size_t)(unsigned)u2 * 20 + cc];
            unsigned v3 = xw[(size_t)(unsigned)u3 * 20 + cc];
            unsigned v4 = xw[(size_t)(unsigned)u4 * 20 + cc];
            unsigned v5 = xw[(size_t)(unsigned)u5 * 20 + cc];
            unsigned v6 = xw[(size_t)(unsigned)u6 * 20 + cc];
            unsigned v7 = xw[(size_t)(unsigned)u7 * 20 + cc];
            float c0 = __int_as_float((int)(u0 >> 32)), c1 = __int_as_float((int)(u1 >> 32));
            float c2 = __int_as_float((int)(u2 >> 32)), c3 = __int_as_float((int)(u3 >> 32));
            float c4 = __int_as_float((int)(u4 >> 32)), c5 = __int_as_float((int)(u5 >> 32));
            float c6 = __int_as_float((int)(u6 >> 32)), c7 = __int_as_float((int)(u7 >> 32));
            float2 f0 = bf2_unpack(v0), f1 = bf2_unpack(v1);
            float2 f2 = bf2_unpack(v2), f3 = bf2_unpack(v3);
            float2 f4 = bf2_unpack(v4), f5 = bf2_unpack(v5);
            float2 f6 = bf2_unpack(v6), f7 = bf2_unpack(v7);
            acc0 += c0 * f0.x + c1 * f1.x + c2 * f2.x + c3 * f3.x
                  + c4 * f4.x + c5 * f5.x + c6 * f6.x + c7 * f7.x;
            acc1 += c0 * f0.y + c1 * f1.y + c2 * f2.y + c3 * f3.y
                  + c4 * f4.y + c5 * f5.y + c6 * f6.y + c7 * f7.y;
        }
        for (; j < re; j++) {
            unsigned long long u = __builtin_nontemporal_load(ep + j);
            float c = __int_as_float((int)(u >> 32));
            float2 f = bf2_unpack(xw[(size_t)(unsigned)u * 20 + cc]);
            acc0 += c * f.x;
            acc1 += c * f.y;
        }
        acc0 = acc0 * di + b0;
        acc1 = acc1 * di + b1;

        float m = act ? fmaxf(acc0, acc1) : -1e30f;
#pragma unroll
        for (int off = 16; off; off >>= 1) m = fmaxf(m, __shfl_xor(m, off));
        float ex = act ? (expf(acc0 - m) + expf(acc1 - m)) : 0.f;
#pragma unroll
        for (int off = 16; off; off >>= 1) ex += __shfl_xor(ex, off);
        float ls = logf(ex);
        if (act && valid)
            *(float2*)&out[(size_t)i * 40 + 2 * col] = make_float2(acc0 - m - ls, acc1 - m - ls);
    }
}

// ---------------------------------------------------------------------------
extern "C" void kernel_launch(void* const* d_in, const int* in_sizes, int n_in,
                              void* d_out, int out_size, void* d_ws, size_t ws_size,
                              hipStream_t stream) {
    const float* x   = (const float*)d_in[0];
    const unsigned* ei = (const unsigned*)d_in[1];
    const float* ew  = (const float*)d_in[2];
    const float* W0  = (const float*)d_in[3];
    const float* b0  = (const float*)d_in[4];
    const float* g0  = (const float*)d_in[5];
    const float* be0 = (const float*)d_in[6];
    const float* W1  = (const float*)d_in[7];
    const float* b1  = (const float*)d_in[8];
    const float* g1  = (const float*)d_in[9];
    const float* be1 = (const float*)d_in[10];
    const float* W2  = (const float*)d_in[11];
    const float* b2  = (const float*)d_in[12];

    const int N = in_sizes[0] / 128;
    const int E = in_sizes[2];
    if (N <= 0 || E <= 0) return;
    const int NB = (N + 255) >> 8;                 // buckets (<=512)
    const int nchunks = (E + CHUNK - 1) / CHUNK;   // partition chunks

    char* ws = (char*)d_ws;
    size_t off = 0;
    auto carve = [&](size_t bytes) {
        char* p = ws + off;
        off += (bytes + 511) & ~((size_t)511);
        return p;
    };
    unsigned* F       = (unsigned*)carve((size_t)N * 64 * 4);  // packed bf162 h
    unsigned* P       = (unsigned*)carve((size_t)N * 64 * 4);  // packed bf162 xw'
    int2*     ep      = (int2*)carve((size_t)E * 8);           // final CSR (src, ew)
    int2*     staging = (int2*)carve((size_t)E * 8);           // bucket-ordered edges
    int*      chist   = (int*)carve((size_t)nchunks * 512 * 4);
    int*      rowptr  = (int*)carve((size_t)(N + 1) * 4);
    float*    dinv    = (float*)carve((size_t)N * 4);
    int*      bhist   = (int*)carve(513 * 4);
    int*      bstart  = (int*)carve(513 * 4);
    int*      bcur    = (int*)carve(513 * 4);
    float*    bn      = (float*)carve(512 * 4);
    int*      flag    = (int*)carve(64);

    hipMemsetAsync(bhist, 0, 513 * 4, stream);
    hipMemsetAsync(flag, 0, 4, stream);

    int nsample = E < 4096 ? E : 4096;
    k_detect<<<(nsample + 255) / 256, 256, 0, stream>>>(ei, nsample, flag);
    int pgrid = nchunks < 1024 ? nchunks : 1024;
    k_bhist<<<pgrid, 256, 0, stream>>>(ei, bhist, chist, flag, E, NB, nchunks);
    k_bscan<<<1, 512, 0, stream>>>(bhist, bstart, bcur, NB);
    k_part<<<pgrid, 256, 0, stream>>>(ei, ew, chist, bcur, staging, flag, E, NB, nchunks);
    k_bucket<<<NB, 256, 0, stream>>>(bstart, staging, rowptr, dinv, ep, N, NB);

    const int gemm_grid = 768;
    const int agg_grid = (N + 63) / 64;
    const unsigned long long* epu = (const unsigned long long*)ep;

    // ---- layer 0 ----
    k_gemm<128, 64, false><<<gemm_grid, 256, 0, stream>>>(x, nullptr, W0, nullptr, nullptr, dinv, P, N);
    hipMemsetAsync(bn, 0, 1024, stream);
    k_agg128<<<agg_grid, 256, 0, stream>>>(P, rowptr, epu, dinv, b0, F, bn, bn + 128, N);
    k_bnfin<<<1, 128, 0, stream>>>(bn, bn + 128, g0, be0, bn + 256, bn + 384, N);

    // ---- layer 1 ----
    k_gemm<128, 64, true><<<gemm_grid, 256, 0, stream>>>(nullptr, F, W1, bn + 256, bn + 384, dinv, P, N);
    hipMemsetAsync(bn, 0, 1024, stream);
    k_agg128<<<agg_grid, 256, 0, stream>>>(P, rowptr, epu, dinv, b1, F, bn, bn + 128, N);
    k_bnfin<<<1, 128, 0, stream>>>(bn, bn + 128, g1, be1, bn + 256, bn + 384, N);

    // ---- layer 2 ----
    k_gemm<40, 128, true><<<gemm_grid, 256, 0, stream>>>(nullptr, F, W2, bn + 256, bn + 384, dinv, P, N);
    k_agg40<<<agg_grid, 256, 0, stream>>>(P, rowptr, epu, dinv, b2, (float*)d_out, N);
}

// Round 8
// 586.786 us; speedup vs baseline: 1.1341x; 1.1341x over previous
//
#include <hip/hip_runtime.h>
#include <math.h>

// ---------------------------------------------------------------------------
// GCN 3-layer forward. Round 7:
//  - MFMA bf16 GEMMs (32x32x16): X rows = A, W^T staged bf16 in LDS = B,
//    fp32 accum, dinv row-scale + bf162 pack epilogue via shfl_xor(1).
//  - Aggregation: 8 nodes/wave (grid 2x) for full occupancy + balance.
// CSR build (round-5 chunk-claimed bucket partition) unchanged.
// FETCH floor note: agg fetch ~205 MB == 8 XCDs x 25.6 MB (per-XCD
// compulsory); random-graph gather cannot go below this.
// ---------------------------------------------------------------------------

#define CHUNK 8192

typedef __attribute__((ext_vector_type(8))) short short8v;
typedef __attribute__((ext_vector_type(16))) float float16v;

__device__ __forceinline__ float2 bf2_unpack(unsigned u) {
    float2 r;
    r.x = __uint_as_float(u << 16);
    r.y = __uint_as_float(u & 0xffff0000u);
    return r;
}
__device__ __forceinline__ unsigned bf2_pack(float a, float b) {
    unsigned ua = __float_as_uint(a);
    unsigned ub = __float_as_uint(b);
    ua = (ua + 0x7fffu + ((ua >> 16) & 1u)) >> 16;
    ub = (ub + 0x7fffu + ((ub >> 16) & 1u)) >> 16;
    return ua | (ub << 16);
}
__device__ __forceinline__ short bf16r(float x) {
    unsigned u = __float_as_uint(x);
    u = (u + 0x7fffu + ((u >> 16) & 1u)) >> 16;
    return (short)u;
}
__device__ __forceinline__ short8v lds_read8(const short* p) {
    short4 lo = *(const short4*)p;
    short4 hi = *(const short4*)(p + 4);
    short8v r;
    r[0] = lo.x; r[1] = lo.y; r[2] = lo.z; r[3] = lo.w;
    r[4] = hi.x; r[5] = hi.y; r[6] = hi.z; r[7] = hi.w;
    return r;
}

// ---------- edge-index dtype detection (int32 vs int64 layout) ----------
__global__ void k_detect(const unsigned* __restrict__ raw, int nsample, int* __restrict__ flag) {
    int i = blockIdx.x * blockDim.x + threadIdx.x;
    if (i < nsample) {
        if (raw[2 * i + 1] != 0u) atomicOr(flag, 1);
    }
}

__device__ __forceinline__ int edge_src(const unsigned* raw, int e, int E, int is64) {
    return is64 ? (int)raw[2 * (size_t)e] : (int)raw[e];
}
__device__ __forceinline__ int edge_dst(const unsigned* raw, int e, int E, int is64) {
    return is64 ? (int)raw[2 * ((size_t)E + e)] : (int)raw[(size_t)E + e];
}

// ---------- per-chunk bucket histograms + merged totals ----------
__global__ __launch_bounds__(256) void k_bhist(const unsigned* __restrict__ raw,
                                               int* __restrict__ bhist, int* __restrict__ chist,
                                               const int* __restrict__ flag,
                                               int E, int NB, int nchunks) {
    __shared__ int h[512];
    int is64 = (*flag == 0);
    for (int c = blockIdx.x; c < nchunks; c += gridDim.x) {
        for (int t = threadIdx.x; t < 512; t += 256) h[t] = 0;
        __syncthreads();
        int base = c * CHUNK;
        int end = (base + CHUNK < E) ? base + CHUNK : E;
        for (int e = base + threadIdx.x; e < end; e += 256) {
            int d = edge_dst(raw, e, E, is64);
            atomicAdd(&h[d >> 8], 1);
        }
        __syncthreads();
        for (int t = threadIdx.x; t < NB; t += 256) {
            int v = h[t];
            chist[(size_t)c * 512 + t] = v;
            if (v) atomicAdd(&bhist[t], v);
        }
        __syncthreads();
    }
}

// ---------- exclusive scan over buckets -> bases + cursors ----------
__global__ __launch_bounds__(512) void k_bscan(const int* __restrict__ bhist,
                                               int* __restrict__ bstart,
                                               int* __restrict__ bcur, int NB) {
    __shared__ int s[512];
    int tid = threadIdx.x;
    int v = (tid < NB) ? bhist[tid] : 0;
    s[tid] = v;
    __syncthreads();
    for (int off = 1; off < 512; off <<= 1) {
        int t = (tid >= off) ? s[tid - off] : 0;
        __syncthreads();
        if (tid >= off) s[tid] += t;
        __syncthreads();
    }
    int ex = s[tid] - v;
    if (tid <= NB) {
        int val = (tid < NB) ? ex : s[NB > 0 ? NB - 1 : 0];
        bstart[tid] = val;
        if (tid < NB) bcur[tid] = val;
    }
}

// ---------- partition: chunk-batched claims, LDS-cursor scatter ----------
__global__ __launch_bounds__(256) void k_part(const unsigned* __restrict__ raw,
                                              const float* __restrict__ ew,
                                              const int* __restrict__ chist,
                                              int* __restrict__ bcur, int2* __restrict__ staging,
                                              const int* __restrict__ flag,
                                              int E, int NB, int nchunks) {
    __shared__ int cur[512];
    int is64 = (*flag == 0);
    for (int c = blockIdx.x; c < nchunks; c += gridDim.x) {
        for (int t = threadIdx.x; t < NB; t += 256) {
            int v = chist[(size_t)c * 512 + t];
            cur[t] = v ? atomicAdd(&bcur[t], v) : 0;
        }
        __syncthreads();
        int base = c * CHUNK;
        int end = (base + CHUNK < E) ? base + CHUNK : E;
        for (int e = base + threadIdx.x; e < end; e += 256) {
            int s = edge_src(raw, e, E, is64);
            int d = edge_dst(raw, e, E, is64);
            float w = ew[e];
            int pos = atomicAdd(&cur[d >> 8], 1);
            staging[pos] = make_int2(s | ((d & 255) << 24), __float_as_int(w));
        }
        __syncthreads();
    }
}

// ---------- per-bucket finalize: rowptr, dinv, local scatter -> ep ----------
__global__ __launch_bounds__(256) void k_bucket(const int* __restrict__ bstart,
                                                const int2* __restrict__ staging,
                                                int* __restrict__ rowptr, float* __restrict__ dinv,
                                                int2* __restrict__ ep, int N, int NB) {
    __shared__ int cnt[256];
    __shared__ float dw[256];
    __shared__ int sc[256];
    __shared__ int cur[256];

    const int b = blockIdx.x;
    const int t = threadIdx.x;
    const int n0 = b << 8;
    const int nn = (N - n0 < 256) ? (N - n0) : 256;
    const int es = bstart[b], ee = bstart[b + 1];

    cnt[t] = 0;
    dw[t] = 0.f;
    __syncthreads();

    for (int j = es + t; j < ee; j += 256) {
        int2 p = staging[j];
        int dl = ((unsigned)p.x) >> 24;
        atomicAdd(&cnt[dl], 1);
        atomicAdd(&dw[dl], __int_as_float(p.y));
    }
    __syncthreads();

    int v = cnt[t];
    sc[t] = v;
    __syncthreads();
    for (int off = 1; off < 256; off <<= 1) {
        int tv = (t >= off) ? sc[t - off] : 0;
        __syncthreads();
        if (t >= off) sc[t] += tv;
        __syncthreads();
    }
    int exoff = sc[t] - v;
    cur[t] = es + exoff;
    if (t < nn) {
        rowptr[n0 + t] = es + exoff;
        dinv[n0 + t] = rsqrtf(dw[t] + 1.0f);
    }
    if (t == 0) rowptr[(n0 + 256 < N) ? (n0 + 256) : N] = ee;
    __syncthreads();

    for (int j = es + t; j < ee; j += 256) {
        int2 p = staging[j];
        int dl = ((unsigned)p.x) >> 24;
        int pos = atomicAdd(&cur[dl], 1);
        ep[pos] = make_int2(p.x & 0x00ffffff, p.y);
    }
}

// ---------- MFMA bf16 GEMM: Yp = pack_bf162( dscale[r] * act(X) @ W ) ----------
// A = X rows (bf16), B = W^T in LDS (bf16), 32x32x16 MFMA, fp32 accum.
// FP32IN: X fp32 [N,128].  BN: Xp packed bf162 [N,64], y=relu(x*sc+sh).
// NCT = DOUT col-tiles of 32 (4 -> each wave 1 ct x 2 row-tiles;
//                             2 -> each wave 1 ct x 1 row-tile).
template <int DOUT, int NCT, bool BN, bool FP32IN>
__global__ __launch_bounds__(256) void k_gemm_mfma(
    const float* __restrict__ Xf, const unsigned* __restrict__ Xp,
    const float* __restrict__ W, const float* __restrict__ scale,
    const float* __restrict__ shift, const float* __restrict__ dscale,
    unsigned* __restrict__ Y, int N)
{
    constexpr int NDW = DOUT / 2;
    constexpr int LDK = 132;                       // padded K stride (bf16)
    constexpr int WROWS = (NCT == 4) ? 128 : 64;   // Wt rows (zero-padded cols)
    constexpr int RTPW = (NCT == 4) ? 2 : 1;       // row-tiles per wave
    __shared__ short Wt[WROWS][LDK];
    __shared__ short As[64][LDK];
    __shared__ float scL[128], shL[128], dscL[64];

    const int tid = threadIdx.x;
    const int wv = tid >> 6, ln = tid & 63;
    const int m = ln & 31, q = ln >> 5;
    const int ct = wv % NCT;
    const int rtbase = (NCT == 4) ? 0 : (wv >> 1);

    if (BN && tid < 128) { scL[tid] = scale[tid]; shL[tid] = shift[tid]; }
    // stage W^T bf16 (once): i -> n = i % WROWS (coalesced W read), k = i / WROWS
    for (int i = tid; i < WROWS * 128; i += 256) {
        int n = i % WROWS, k = i / WROWS;
        float w = (n < DOUT) ? W[k * DOUT + n] : 0.f;
        Wt[n][k] = bf16r(w);
    }

    for (int base = blockIdx.x * 64; base < N; base += gridDim.x * 64) {
        __syncthreads();  // previous iter done with As
        // ---- stage 64 rows of X (bf16) + dscale ----
        if (FP32IN) {
            for (int i = tid; i < 64 * 32; i += 256) {
                int r = i >> 5, s = i & 31;
                int row = base + r;
                float4 v = make_float4(0.f, 0.f, 0.f, 0.f);
                if (row < N) v = ((const float4*)(Xf + (size_t)row * 128))[s];
                short4 qv = make_short4(bf16r(v.x), bf16r(v.y), bf16r(v.z), bf16r(v.w));
                *(short4*)&As[r][s * 4] = qv;
            }
        } else {
            for (int i = tid; i < 64 * 16; i += 256) {
                int r = i >> 4, s = i & 15;
                int row = base + r;
                uint4 u = make_uint4(0, 0, 0, 0);
                if (row < N) u = ((const uint4*)(Xp + (size_t)row * 64))[s];
                unsigned uu[4] = {u.x, u.y, u.z, u.w};
                short vv[8];
#pragma unroll
                for (int d = 0; d < 4; d++) {
                    float2 f = bf2_unpack(uu[d]);
                    int fi = s * 8 + 2 * d;
                    f.x = fmaxf(f.x * scL[fi] + shL[fi], 0.f);
                    f.y = fmaxf(f.y * scL[fi + 1] + shL[fi + 1], 0.f);
                    vv[2 * d] = bf16r(f.x);
                    vv[2 * d + 1] = bf16r(f.y);
                }
                *(short4*)&As[r][s * 8] = make_short4(vv[0], vv[1], vv[2], vv[3]);
                *(short4*)&As[r][s * 8 + 4] = make_short4(vv[4], vv[5], vv[6], vv[7]);
            }
        }
        if (tid < 64) {
            int row = base + tid;
            dscL[tid] = (row < N) ? dscale[row] : 0.f;
        }
        __syncthreads();

        // ---- MFMA K-loop ----
        float16v acc[RTPW];
#pragma unroll
        for (int rt = 0; rt < RTPW; rt++)
#pragma unroll
            for (int r = 0; r < 16; r++) acc[rt][r] = 0.f;

#pragma unroll
        for (int kc = 0; kc < 8; kc++) {
            int kb = kc * 16 + q * 8;
            short8v bfrag = lds_read8(&Wt[ct * 32 + m][kb]);
#pragma unroll
            for (int rt = 0; rt < RTPW; rt++) {
                int rtg = (NCT == 4) ? rt : rtbase;
                short8v afrag = lds_read8(&As[rtg * 32 + m][kb]);
                acc[rt] = __builtin_amdgcn_mfma_f32_32x32x16_bf16(afrag, bfrag, acc[rt], 0, 0, 0);
            }
        }

        // ---- epilogue: dscale, pack col-pairs via shfl_xor(1), nt-store ----
#pragma unroll
        for (int rt = 0; rt < RTPW; rt++) {
            int rtg = (NCT == 4) ? rt : rtbase;
#pragma unroll
            for (int r = 0; r < 16; r++) {
                int rowl = rtg * 32 + (r & 3) + 8 * (r >> 2) + 4 * q;
                float v = acc[rt][r] * dscL[rowl];
                float pv = __shfl_xor(v, 1);
                if (!(ln & 1)) {
                    int row = base + rowl;
                    int cp = ct * 16 + (m >> 1);
                    if (row < N && cp < NDW)
                        __builtin_nontemporal_store(bf2_pack(v, pv), &Y[(size_t)row * NDW + cp]);
                }
            }
        }
    }
}

// ---------- aggregation (128-wide) -> packed bf16 h (nt) + BN partials ----------
__global__ __launch_bounds__(256) void k_agg128(
    const unsigned* __restrict__ xw, const int* __restrict__ rowptr,
    const unsigned long long* __restrict__ ep, const float* __restrict__ dinv,
    const float* __restrict__ bias, unsigned* __restrict__ h,
    float* __restrict__ bn_sum, float* __restrict__ bn_sq, int N)
{
    __shared__ float redS[512], redQ[512];
    const int lane = threadIdx.x & 63;
    const int wave = threadIdx.x >> 6;
    const int base = blockIdx.x * 32 + wave * 8;
    const float b0 = bias[2 * lane], b1 = bias[2 * lane + 1];
    float s0 = 0.f, s1 = 0.f, q0 = 0.f, q1 = 0.f;

    const int nmax = (N - base < 8) ? (N - base) : 8;
    for (int n = 0; n < nmax; n++) {
        const int i = base + n;
        const int rs = rowptr[i], re = rowptr[i + 1];
        const float di = dinv[i];
        float2 sv = bf2_unpack(xw[(size_t)i * 64 + lane]);
        float acc0 = sv.x, acc1 = sv.y;
        int j = rs;
        for (; j + 8 <= re; j += 8) {
            unsigned long long u0 = __builtin_nontemporal_load(ep + j);
            unsigned long long u1 = __builtin_nontemporal_load(ep + j + 1);
            unsigned long long u2 = __builtin_nontemporal_load(ep + j + 2);
            unsigned long long u3 = __builtin_nontemporal_load(ep + j + 3);
            unsigned long long u4 = __builtin_nontemporal_load(ep + j + 4);
            unsigned long long u5 = __builtin_nontemporal_load(ep + j + 5);
            unsigned long long u6 = __builtin_nontemporal_load(ep + j + 6);
            unsigned long long u7 = __builtin_nontemporal_load(ep + j + 7);
            unsigned v0 = xw[(size_t)(unsigned)u0 * 64 + lane];
            unsigned v1 = xw[(size_t)(unsigned)u1 * 64 + lane];
            unsigned v2 = xw[(size_t)(unsigned)u2 * 64 + lane];
            unsigned v3 = xw[(size_t)(unsigned)u3 * 64 + lane];
            unsigned v4 = xw[(size_t)(unsigned)u4 * 64 + lane];
            unsigned v5 = xw[(size_t)(unsigned)u5 * 64 + lane];
            unsigned v6 = xw[(size_t)(unsigned)u6 * 64 + lane];
            unsigned v7 = xw[(size_t)(unsigned)u7 * 64 + lane];
            float c0 = __int_as_float((int)(u0 >> 32)), c1 = __int_as_float((int)(u1 >> 32));
            float c2 = __int_as_float((int)(u2 >> 32)), c3 = __int_as_float((int)(u3 >> 32));
            float c4 = __int_as_float((int)(u4 >> 32)), c5 = __int_as_float((int)(u5 >> 32));
            float c6 = __int_as_float((int)(u6 >> 32)), c7 = __int_as_float((int)(u7 >> 32));
            float2 f0 = bf2_unpack(v0), f1 = bf2_unpack(v1);
            float2 f2 = bf2_unpack(v2), f3 = bf2_unpack(v3);
            float2 f4 = bf2_unpack(v4), f5 = bf2_unpack(v5);
            float2 f6 = bf2_unpack(v6), f7 = bf2_unpack(v7);
            acc0 += c0 * f0.x + c1 * f1.x + c2 * f2.x + c3 * f3.x
                  + c4 * f4.x + c5 * f5.x + c6 * f6.x + c7 * f7.x;
            acc1 += c0 * f0.y + c1 * f1.y + c2 * f2.y + c3 * f3.y
                  + c4 * f4.y + c5 * f5.y + c6 * f6.y + c7 * f7.y;
        }
        for (; j + 4 <= re; j += 4) {
            unsigned long long u0 = __builtin_nontemporal_load(ep + j);
            unsigned long long u1 = __builtin_nontemporal_load(ep + j + 1);
            unsigned long long u2 = __builtin_nontemporal_load(ep + j + 2);
            unsigned long long u3 = __builtin_nontemporal_load(ep + j + 3);
            unsigned v0 = xw[(size_t)(unsigned)u0 * 64 + lane];
            unsigned v1 = xw[(size_t)(unsigned)u1 * 64 + lane];
            unsigned v2 = xw[(size_t)(unsigned)u2 * 64 + lane];
            unsigned v3 = xw[(size_t)(unsigned)u3 * 64 + lane];
            float c0 = __int_as_float((int)(u0 >> 32)), c1 = __int_as_float((int)(u1 >> 32));
            float c2 = __int_as_float((int)(u2 >> 32)), c3 = __int_as_float((int)(u3 >> 32));
            float2 f0 = bf2_unpack(v0), f1 = bf2_unpack(v1);
            float2 f2 = bf2_unpack(v2), f3 = bf2_unpack(v3);
            acc0 += c0 * f0.x + c1 * f1.x + c2 * f2.x + c3 * f3.x;
            acc1 += c0 * f0.y + c1 * f1.y + c2 * f2.y + c3 * f3.y;
        }
        for (; j < re; j++) {
            unsigned long long u = __builtin_nontemporal_load(ep + j);
            float c = __int_as_float((int)(u >> 32));
            float2 f = bf2_unpack(xw[(size_t)(unsigned)u * 64 + lane]);
            acc0 += c * f.x;
            acc1 += c * f.y;
        }
        acc0 = acc0 * di + b0;
        acc1 = acc1 * di + b1;
        __builtin_nontemporal_store(bf2_pack(acc0, acc1), &h[(size_t)i * 64 + lane]);
        s0 += acc0; s1 += acc1; q0 += acc0 * acc0; q1 += acc1 * acc1;
    }

    redS[wave * 128 + 2 * lane] = s0;
    redS[wave * 128 + 2 * lane + 1] = s1;
    redQ[wave * 128 + 2 * lane] = q0;
    redQ[wave * 128 + 2 * lane + 1] = q1;
    __syncthreads();
    if (threadIdx.x < 128) {
        int f = threadIdx.x;
        float ts = redS[f] + redS[128 + f] + redS[256 + f] + redS[384 + f];
        float tq = redQ[f] + redQ[128 + f] + redQ[256 + f] + redQ[384 + f];
        atomicAdd(&bn_sum[f], ts);
        atomicAdd(&bn_sq[f], tq);
    }
}

// ---------- BN finalize ----------
__global__ void k_bnfin(const float* __restrict__ bn_sum, const float* __restrict__ bn_sq,
                        const float* __restrict__ gamma, const float* __restrict__ beta,
                        float* __restrict__ scale, float* __restrict__ shift, int N) {
    int f = threadIdx.x;
    float inv = 1.0f / (float)N;
    float m = bn_sum[f] * inv;
    float v = bn_sq[f] * inv - m * m;
    float sc = gamma[f] * rsqrtf(v + 1e-5f);
    scale[f] = sc;
    shift[f] = beta[f] - m * sc;
}

// ---------- aggregation (40-wide, bf16 gather) + bias + log_softmax ----------
__global__ __launch_bounds__(256) void k_agg40(
    const unsigned* __restrict__ xw, const int* __restrict__ rowptr,
    const unsigned long long* __restrict__ ep, const float* __restrict__ dinv,
    const float* __restrict__ bias, float* __restrict__ out, int N)
{
    const int lane = threadIdx.x & 63;
    const int wave = threadIdx.x >> 6;
    const int half = lane >> 5;
    const int col = lane & 31;
    const bool act = col < 20;
    const int base = blockIdx.x * 32 + wave * 8;
    if (base >= N) return;
    const int cc = act ? col : 0;
    const float b0 = act ? bias[2 * col] : 0.f;
    const float b1 = act ? bias[2 * col + 1] : 0.f;

    for (int n = 0; n < 8; n += 2) {
        const int i = base + n + half;
        const bool valid = i < N;
        const int ic = valid ? i : 0;
        const int rs = rowptr[ic];
        int re = rowptr[ic + 1];
        re = valid ? re : rs;
        const float di = dinv[ic];
        float2 sv = bf2_unpack(xw[(size_t)ic * 20 + cc]);
        float acc0 = sv.x, acc1 = sv.y;
        int j = rs;
        for (; j + 8 <= re; j += 8) {
            unsigned long long u0 = __builtin_nontemporal_load(ep + j);
            unsigned long long u1 = __builtin_nontemporal_load(ep + j + 1);
            unsigned long long u2 = __builtin_nontemporal_load(ep + j + 2);
            unsigned long long u3 = __builtin_nontemporal_load(ep + j + 3);
            unsigned long long u4 = __builtin_nontemporal_load(ep + j + 4);
            unsigned long long u5 = __builtin_nontemporal_load(ep + j + 5);
            unsigned long long u6 = __builtin_nontemporal_load(ep + j + 6);
            unsigned long long u7 = __builtin_nontemporal_load(ep + j + 7);
            unsigned v0 = xw[(size_t)(unsigned)u0 * 20 + cc];
            unsigned v1 = xw[(size_t)(unsigned)u1 * 20 + cc];
            unsigned v2 = xw[(size_t)(unsigned)u2 * 20 + cc];
            unsigned v3 = xw[(size_t)(unsigned)u3 * 20 + cc];
            unsigned v4 = xw[(size_t)(unsigned)u4 * 20 + cc];
            unsigned v5 = xw[(size_t)(unsigned)u5 * 20 + cc];
            unsigned v6 = xw[(size_t)(unsigned)u6 * 20 + cc];
            unsigned v7 = xw[(size_t)(unsigned)u7 * 20 + cc];
            float c0 = __int_as_float((int)(u0 >> 32)), c1 = __int_as_float((int)(u1 >> 32));
            float c2 = __int_as_float((int)(u2 >> 32)), c3 = __int_as_float((int)(u3 >> 32));
            float c4 = __int_as_float((int)(u4 >> 32)), c5 = __int_as_float((int)(u5 >> 32));
            float c6 = __int_as_float((int)(u6 >> 32)), c7 = __int_as_float((int)(u7 >> 32));
            float2 f0 = bf2_unpack(v0), f1 = bf2_unpack(v1);
            float2 f2 = bf2_unpack(v2), f3 = bf2_unpack(v3);
            float2 f4 = bf2_unpack(v4), f5 = bf2_unpack(v5);
            float2 f6 = bf2_unpack(v6), f7 = bf2_unpack(v7);
            acc0 += c0 * f0.x + c1 * f1.x + c2 * f2.x + c3 * f3.x
                  + c4 * f4.x + c5 * f5.x + c6 * f6.x + c7 * f7.x;
            acc1 += c0 * f0.y + c1 * f1.y + c2 * f2.y + c3 * f3.y
                  + c4 * f4.y + c5 * f5.y + c6 * f6.y + c7 * f7.y;
        }
        for (; j < re; j++) {
            unsigned long long u = __builtin_nontemporal_load(ep + j);
            float c = __int_as_float((int)(u >> 32));
            float2 f = bf2_unpack(xw[(size_t)(unsigned)u * 20 + cc]);
            acc0 += c * f.x;
            acc1 += c * f.y;
        }
        acc0 = acc0 * di + b0;
        acc1 = acc1 * di + b1;

        float m = act ? fmaxf(acc0, acc1) : -1e30f;
#pragma unroll
        for (int off = 16; off; off >>= 1) m = fmaxf(m, __shfl_xor(m, off));
        float ex = act ? (expf(acc0 - m) + expf(acc1 - m)) : 0.f;
#pragma unroll
        for (int off = 16; off; off >>= 1) ex += __shfl_xor(ex, off);
        float ls = logf(ex);
        if (act && valid)
            *(float2*)&out[(size_t)i * 40 + 2 * col] = make_float2(acc0 - m - ls, acc1 - m - ls);
    }
}

// ---------------------------------------------------------------------------
extern "C" void kernel_launch(void* const* d_in, const int* in_sizes, int n_in,
                              void* d_out, int out_size, void* d_ws, size_t ws_size,
                              hipStream_t stream) {
    const float* x   = (const float*)d_in[0];
    const unsigned* ei = (const unsigned*)d_in[1];
    const float* ew  = (const float*)d_in[2];
    const float* W0  = (const float*)d_in[3];
    const float* b0  = (const float*)d_in[4];
    const float* g0  = (const float*)d_in[5];
    const float* be0 = (const float*)d_in[6];
    const float* W1  = (const float*)d_in[7];
    const float* b1  = (const float*)d_in[8];
    const float* g1  = (const float*)d_in[9];
    const float* be1 = (const float*)d_in[10];
    const float* W2  = (const float*)d_in[11];
    const float* b2  = (const float*)d_in[12];

    const int N = in_sizes[0] / 128;
    const int E = in_sizes[2];
    if (N <= 0 || E <= 0) return;
    const int NB = (N + 255) >> 8;
    const int nchunks = (E + CHUNK - 1) / CHUNK;

    char* ws = (char*)d_ws;
    size_t off = 0;
    auto carve = [&](size_t bytes) {
        char* p = ws + off;
        off += (bytes + 511) & ~((size_t)511);
        return p;
    };
    unsigned* F       = (unsigned*)carve((size_t)N * 64 * 4);  // packed bf162 h
    unsigned* P       = (unsigned*)carve((size_t)N * 64 * 4);  // packed bf162 xw'
    int2*     ep      = (int2*)carve((size_t)E * 8);
    int2*     staging = (int2*)carve((size_t)E * 8);
    int*      chist   = (int*)carve((size_t)nchunks * 512 * 4);
    int*      rowptr  = (int*)carve((size_t)(N + 1) * 4);
    float*    dinv    = (float*)carve((size_t)N * 4);
    int*      bhist   = (int*)carve(513 * 4);
    int*      bstart  = (int*)carve(513 * 4);
    int*      bcur    = (int*)carve(513 * 4);
    float*    bn      = (float*)carve(512 * 4);
    int*      flag    = (int*)carve(64);

    hipMemsetAsync(bhist, 0, 513 * 4, stream);
    hipMemsetAsync(flag, 0, 4, stream);

    int nsample = E < 4096 ? E : 4096;
    k_detect<<<(nsample + 255) / 256, 256, 0, stream>>>(ei, nsample, flag);
    int pgrid = nchunks < 1024 ? nchunks : 1024;
    k_bhist<<<pgrid, 256, 0, stream>>>(ei, bhist, chist, flag, E, NB, nchunks);
    k_bscan<<<1, 512, 0, stream>>>(bhist, bstart, bcur, NB);
    k_part<<<pgrid, 256, 0, stream>>>(ei, ew, chist, bcur, staging, flag, E, NB, nchunks);
    k_bucket<<<NB, 256, 0, stream>>>(bstart, staging, rowptr, dinv, ep, N, NB);

    const int agg_grid = (N + 31) / 32;
    const unsigned long long* epu = (const unsigned long long*)ep;

    // ---- layer 0 ----
    k_gemm_mfma<128, 4, false, true><<<1024, 256, 0, stream>>>(x, nullptr, W0, nullptr, nullptr, dinv, P, N);
    hipMemsetAsync(bn, 0, 1024, stream);
    k_agg128<<<agg_grid, 256, 0, stream>>>(P, rowptr, epu, dinv, b0, F, bn, bn + 128, N);
    k_bnfin<<<1, 128, 0, stream>>>(bn, bn + 128, g0, be0, bn + 256, bn + 384, N);

    // ---- layer 1 ----
    k_gemm_mfma<128, 4, true, false><<<1024, 256, 0, stream>>>(nullptr, F, W1, bn + 256, bn + 384, dinv, P, N);
    hipMemsetAsync(bn, 0, 1024, stream);
    k_agg128<<<agg_grid, 256, 0, stream>>>(P, rowptr, epu, dinv, b1, F, bn, bn + 128, N);
    k_bnfin<<<1, 128, 0, stream>>>(bn, bn + 128, g1, be1, bn + 256, bn + 384, N);

    // ---- layer 2 ----
    k_gemm_mfma<40, 2, true, false><<<1024, 256, 0, stream>>>(nullptr, F, W2, bn + 256, bn + 384, dinv, P, N);
    k_agg40<<<agg_grid, 256, 0, stream>>>(P, rowptr, epu, dinv, b2, (float*)d_out, N);
}

// Round 9
// 578.261 us; speedup vs baseline: 1.1508x; 1.0147x over previous
//
#include <hip/hip_runtime.h>
#include <math.h>

// ---------------------------------------------------------------------------
// GCN 3-layer forward. Round 9: revert agg to 16 nodes/wave (round-8's
// 8/wave occupancy "fix" regressed: gather is XCD-fabric/MSHR-bound, extra
// waves thrash L2) + dispatch-count diet:
//   - k_detect/flag dropped: chunk kernels self-detect int64 layout
//   - bhist array dropped: k_bscan sums per-chunk hists directly
//   - bn memsets dropped: GEMM block 0 zeros BN accumulators
// MFMA GEMMs + chunk-claimed bucket CSR build unchanged from round 8.
// agg FETCH ~205 MB == 8 XCDs x 25.6 MB per-XCD compulsory (structural).
// ---------------------------------------------------------------------------

#define CHUNK 8192

typedef __attribute__((ext_vector_type(8))) short short8v;
typedef __attribute__((ext_vector_type(16))) float float16v;

__device__ __forceinline__ float2 bf2_unpack(unsigned u) {
    float2 r;
    r.x = __uint_as_float(u << 16);
    r.y = __uint_as_float(u & 0xffff0000u);
    return r;
}
__device__ __forceinline__ unsigned bf2_pack(float a, float b) {
    unsigned ua = __float_as_uint(a);
    unsigned ub = __float_as_uint(b);
    ua = (ua + 0x7fffu + ((ua >> 16) & 1u)) >> 16;
    ub = (ub + 0x7fffu + ((ub >> 16) & 1u)) >> 16;
    return ua | (ub << 16);
}
__device__ __forceinline__ short bf16r(float x) {
    unsigned u = __float_as_uint(x);
    u = (u + 0x7fffu + ((u >> 16) & 1u)) >> 16;
    return (short)u;
}
__device__ __forceinline__ short8v lds_read8(const short* p) {
    short4 lo = *(const short4*)p;
    short4 hi = *(const short4*)(p + 4);
    short8v r;
    r[0] = lo.x; r[1] = lo.y; r[2] = lo.z; r[3] = lo.w;
    r[4] = hi.x; r[5] = hi.y; r[6] = hi.z; r[7] = hi.w;
    return r;
}

__device__ __forceinline__ int edge_src(const unsigned* raw, int e, int E, int is64) {
    return is64 ? (int)raw[2 * (size_t)e] : (int)raw[e];
}
__device__ __forceinline__ int edge_dst(const unsigned* raw, int e, int E, int is64) {
    return is64 ? (int)raw[2 * ((size_t)E + e)] : (int)raw[(size_t)E + e];
}

// Per-chunk int64-layout self-detection: int64 edge ids < 2^31 have all odd
// dwords zero; int32 random node-id data has nonzero odd dwords w.p. ~1.
__device__ __forceinline__ int chunk_is64(const unsigned* raw, int base, int end,
                                          int tid, int* lflag) {
    if (tid == 0) *lflag = 0;
    __syncthreads();
    int any = 0;
    for (int e = base + tid; e < end; e += 256)
        any |= (raw[2 * (size_t)e + 1] != 0u);
    if (any) *lflag = 1;
    __syncthreads();
    return (*lflag == 0);
}

// ---------- per-chunk bucket histograms ----------
__global__ __launch_bounds__(256) void k_bhist(const unsigned* __restrict__ raw,
                                               int* __restrict__ chist,
                                               int E, int NB, int nchunks) {
    __shared__ int h[512];
    __shared__ int lflag;
    for (int c = blockIdx.x; c < nchunks; c += gridDim.x) {
        int base = c * CHUNK;
        int end = (base + CHUNK < E) ? base + CHUNK : E;
        int is64 = chunk_is64(raw, base, end, threadIdx.x, &lflag);
        for (int t = threadIdx.x; t < 512; t += 256) h[t] = 0;
        __syncthreads();
        for (int e = base + threadIdx.x; e < end; e += 256) {
            int d = edge_dst(raw, e, E, is64);
            atomicAdd(&h[d >> 8], 1);
        }
        __syncthreads();
        for (int t = threadIdx.x; t < NB; t += 256)
            chist[(size_t)c * 512 + t] = h[t];
        __syncthreads();
    }
}

// ---------- sum chunk hists + exclusive scan -> bases + cursors ----------
__global__ __launch_bounds__(512) void k_bscan(const int* __restrict__ chist,
                                               int* __restrict__ bstart,
                                               int* __restrict__ bcur,
                                               int NB, int nchunks) {
    __shared__ int s[512];
    int tid = threadIdx.x;
    int v = 0;
    if (tid < NB)
        for (int c = 0; c < nchunks; c++) v += chist[(size_t)c * 512 + tid];
    s[tid] = v;
    __syncthreads();
    for (int off = 1; off < 512; off <<= 1) {
        int t = (tid >= off) ? s[tid - off] : 0;
        __syncthreads();
        if (tid >= off) s[tid] += t;
        __syncthreads();
    }
    int ex = s[tid] - v;
    if (tid <= NB) {
        int val = (tid < NB) ? ex : s[NB > 0 ? NB - 1 : 0];
        bstart[tid] = val;
        if (tid < NB) bcur[tid] = val;
    }
}

// ---------- partition: chunk-batched claims, LDS-cursor scatter ----------
__global__ __launch_bounds__(256) void k_part(const unsigned* __restrict__ raw,
                                              const float* __restrict__ ew,
                                              const int* __restrict__ chist,
                                              int* __restrict__ bcur, int2* __restrict__ staging,
                                              int E, int NB, int nchunks) {
    __shared__ int cur[512];
    __shared__ int lflag;
    for (int c = blockIdx.x; c < nchunks; c += gridDim.x) {
        int base = c * CHUNK;
        int end = (base + CHUNK < E) ? base + CHUNK : E;
        int is64 = chunk_is64(raw, base, end, threadIdx.x, &lflag);
        for (int t = threadIdx.x; t < NB; t += 256) {
            int v = chist[(size_t)c * 512 + t];
            cur[t] = v ? atomicAdd(&bcur[t], v) : 0;
        }
        __syncthreads();
        for (int e = base + threadIdx.x; e < end; e += 256) {
            int s = edge_src(raw, e, E, is64);
            int d = edge_dst(raw, e, E, is64);
            float w = ew[e];
            int pos = atomicAdd(&cur[d >> 8], 1);
            staging[pos] = make_int2(s | ((d & 255) << 24), __float_as_int(w));
        }
        __syncthreads();
    }
}

// ---------- per-bucket finalize: rowptr, dinv, local scatter -> ep ----------
__global__ __launch_bounds__(256) void k_bucket(const int* __restrict__ bstart,
                                                const int2* __restrict__ staging,
                                                int* __restrict__ rowptr, float* __restrict__ dinv,
                                                int2* __restrict__ ep, int N, int NB) {
    __shared__ int cnt[256];
    __shared__ float dw[256];
    __shared__ int sc[256];
    __shared__ int cur[256];

    const int b = blockIdx.x;
    const int t = threadIdx.x;
    const int n0 = b << 8;
    const int nn = (N - n0 < 256) ? (N - n0) : 256;
    const int es = bstart[b], ee = bstart[b + 1];

    cnt[t] = 0;
    dw[t] = 0.f;
    __syncthreads();

    for (int j = es + t; j < ee; j += 256) {
        int2 p = staging[j];
        int dl = ((unsigned)p.x) >> 24;
        atomicAdd(&cnt[dl], 1);
        atomicAdd(&dw[dl], __int_as_float(p.y));
    }
    __syncthreads();

    int v = cnt[t];
    sc[t] = v;
    __syncthreads();
    for (int off = 1; off < 256; off <<= 1) {
        int tv = (t >= off) ? sc[t - off] : 0;
        __syncthreads();
        if (t >= off) sc[t] += tv;
        __syncthreads();
    }
    int exoff = sc[t] - v;
    cur[t] = es + exoff;
    if (t < nn) {
        rowptr[n0 + t] = es + exoff;
        dinv[n0 + t] = rsqrtf(dw[t] + 1.0f);
    }
    if (t == 0) rowptr[(n0 + 256 < N) ? (n0 + 256) : N] = ee;
    __syncthreads();

    for (int j = es + t; j < ee; j += 256) {
        int2 p = staging[j];
        int dl = ((unsigned)p.x) >> 24;
        int pos = atomicAdd(&cur[dl], 1);
        ep[pos] = make_int2(p.x & 0x00ffffff, p.y);
    }
}

// ---------- MFMA bf16 GEMM: Yp = pack_bf162( dscale[r] * act(X) @ W ) ----------
// Block 0 additionally zeros bnacc[0:256] (BN accumulators for the following
// aggregation) -- saves a memset dispatch; safe since agg runs after.
template <int DOUT, int NCT, bool BN, bool FP32IN>
__global__ __launch_bounds__(256) void k_gemm_mfma(
    const float* __restrict__ Xf, const unsigned* __restrict__ Xp,
    const float* __restrict__ W, const float* __restrict__ scale,
    const float* __restrict__ shift, const float* __restrict__ dscale,
    unsigned* __restrict__ Y, float* __restrict__ bnacc, int N)
{
    constexpr int NDW = DOUT / 2;
    constexpr int LDK = 132;
    constexpr int WROWS = (NCT == 4) ? 128 : 64;
    constexpr int RTPW = (NCT == 4) ? 2 : 1;
    __shared__ short Wt[WROWS][LDK];
    __shared__ short As[64][LDK];
    __shared__ float scL[128], shL[128], dscL[64];

    const int tid = threadIdx.x;
    const int wv = tid >> 6, ln = tid & 63;
    const int m = ln & 31, q = ln >> 5;
    const int ct = wv % NCT;
    const int rtbase = (NCT == 4) ? 0 : (wv >> 1);

    if (bnacc && blockIdx.x == 0) bnacc[tid] = 0.f;
    if (BN && tid < 128) { scL[tid] = scale[tid]; shL[tid] = shift[tid]; }
    for (int i = tid; i < WROWS * 128; i += 256) {
        int n = i % WROWS, k = i / WROWS;
        float w = (n < DOUT) ? W[k * DOUT + n] : 0.f;
        Wt[n][k] = bf16r(w);
    }

    for (int base = blockIdx.x * 64; base < N; base += gridDim.x * 64) {
        __syncthreads();
        if (FP32IN) {
            for (int i = tid; i < 64 * 32; i += 256) {
                int r = i >> 5, s = i & 31;
                int row = base + r;
                float4 v = make_float4(0.f, 0.f, 0.f, 0.f);
                if (row < N) v = ((const float4*)(Xf + (size_t)row * 128))[s];
                short4 qv = make_short4(bf16r(v.x), bf16r(v.y), bf16r(v.z), bf16r(v.w));
                *(short4*)&As[r][s * 4] = qv;
            }
        } else {
            for (int i = tid; i < 64 * 16; i += 256) {
                int r = i >> 4, s = i & 15;
                int row = base + r;
                uint4 u = make_uint4(0, 0, 0, 0);
                if (row < N) u = ((const uint4*)(Xp + (size_t)row * 64))[s];
                unsigned uu[4] = {u.x, u.y, u.z, u.w};
                short vv[8];
#pragma unroll
                for (int d = 0; d < 4; d++) {
                    float2 f = bf2_unpack(uu[d]);
                    int fi = s * 8 + 2 * d;
                    f.x = fmaxf(f.x * scL[fi] + shL[fi], 0.f);
                    f.y = fmaxf(f.y * scL[fi + 1] + shL[fi + 1], 0.f);
                    vv[2 * d] = bf16r(f.x);
                    vv[2 * d + 1] = bf16r(f.y);
                }
                *(short4*)&As[r][s * 8] = make_short4(vv[0], vv[1], vv[2], vv[3]);
                *(short4*)&As[r][s * 8 + 4] = make_short4(vv[4], vv[5], vv[6], vv[7]);
            }
        }
        if (tid < 64) {
            int row = base + tid;
            dscL[tid] = (row < N) ? dscale[row] : 0.f;
        }
        __syncthreads();

        float16v acc[RTPW];
#pragma unroll
        for (int rt = 0; rt < RTPW; rt++)
#pragma unroll
            for (int r = 0; r < 16; r++) acc[rt][r] = 0.f;

#pragma unroll
        for (int kc = 0; kc < 8; kc++) {
            int kb = kc * 16 + q * 8;
            short8v bfrag = lds_read8(&Wt[ct * 32 + m][kb]);
#pragma unroll
            for (int rt = 0; rt < RTPW; rt++) {
                int rtg = (NCT == 4) ? rt : rtbase;
                short8v afrag = lds_read8(&As[rtg * 32 + m][kb]);
                acc[rt] = __builtin_amdgcn_mfma_f32_32x32x16_bf16(afrag, bfrag, acc[rt], 0, 0, 0);
            }
        }

#pragma unroll
        for (int rt = 0; rt < RTPW; rt++) {
            int rtg = (NCT == 4) ? rt : rtbase;
#pragma unroll
            for (int r = 0; r < 16; r++) {
                int rowl = rtg * 32 + (r & 3) + 8 * (r >> 2) + 4 * q;
                float v = acc[rt][r] * dscL[rowl];
                float pv = __shfl_xor(v, 1);
                if (!(ln & 1)) {
                    int row = base + rowl;
                    int cp = ct * 16 + (m >> 1);
                    if (row < N && cp < NDW)
                        __builtin_nontemporal_store(bf2_pack(v, pv), &Y[(size_t)row * NDW + cp]);
                }
            }
        }
    }
}

// ---------- aggregation (128-wide) -> packed bf16 h (nt) + BN partials ----------
__global__ __launch_bounds__(256) void k_agg128(
    const unsigned* __restrict__ xw, const int* __restrict__ rowptr,
    const unsigned long long* __restrict__ ep, const float* __restrict__ dinv,
    const float* __restrict__ bias, unsigned* __restrict__ h,
    float* __restrict__ bn_sum, float* __restrict__ bn_sq, int N)
{
    __shared__ float redS[512], redQ[512];
    const int lane = threadIdx.x & 63;
    const int wave = threadIdx.x >> 6;
    const int base = blockIdx.x * 64 + wave * 16;
    const float b0 = bias[2 * lane], b1 = bias[2 * lane + 1];
    float s0 = 0.f, s1 = 0.f, q0 = 0.f, q1 = 0.f;

    const int nmax = (N - base < 16) ? (N - base) : 16;
    for (int n = 0; n < nmax; n++) {
        const int i = base + n;
        const int rs = rowptr[i], re = rowptr[i + 1];
        const float di = dinv[i];
        float2 sv = bf2_unpack(xw[(size_t)i * 64 + lane]);
        float acc0 = sv.x, acc1 = sv.y;
        int j = rs;
        for (; j + 8 <= re; j += 8) {
            unsigned long long u0 = __builtin_nontemporal_load(ep + j);
            unsigned long long u1 = __builtin_nontemporal_load(ep + j + 1);
            unsigned long long u2 = __builtin_nontemporal_load(ep + j + 2);
            unsigned long long u3 = __builtin_nontemporal_load(ep + j + 3);
            unsigned long long u4 = __builtin_nontemporal_load(ep + j + 4);
            unsigned long long u5 = __builtin_nontemporal_load(ep + j + 5);
            unsigned long long u6 = __builtin_nontemporal_load(ep + j + 6);
            unsigned long long u7 = __builtin_nontemporal_load(ep + j + 7);
            unsigned v0 = xw[(size_t)(unsigned)u0 * 64 + lane];
            unsigned v1 = xw[(size_t)(unsigned)u1 * 64 + lane];
            unsigned v2 = xw[(size_t)(unsigned)u2 * 64 + lane];
            unsigned v3 = xw[(size_t)(unsigned)u3 * 64 + lane];
            unsigned v4 = xw[(size_t)(unsigned)u4 * 64 + lane];
            unsigned v5 = xw[(size_t)(unsigned)u5 * 64 + lane];
            unsigned v6 = xw[(size_t)(unsigned)u6 * 64 + lane];
            unsigned v7 = xw[(size_t)(unsigned)u7 * 64 + lane];
            float c0 = __int_as_float((int)(u0 >> 32)), c1 = __int_as_float((int)(u1 >> 32));
            float c2 = __int_as_float((int)(u2 >> 32)), c3 = __int_as_float((int)(u3 >> 32));
            float c4 = __int_as_float((int)(u4 >> 32)), c5 = __int_as_float((int)(u5 >> 32));
            float c6 = __int_as_float((int)(u6 >> 32)), c7 = __int_as_float((int)(u7 >> 32));
            float2 f0 = bf2_unpack(v0), f1 = bf2_unpack(v1);
            float2 f2 = bf2_unpack(v2), f3 = bf2_unpack(v3);
            float2 f4 = bf2_unpack(v4), f5 = bf2_unpack(v5);
            float2 f6 = bf2_unpack(v6), f7 = bf2_unpack(v7);
            acc0 += c0 * f0.x + c1 * f1.x + c2 * f2.x + c3 * f3.x
                  + c4 * f4.x + c5 * f5.x + c6 * f6.x + c7 * f7.x;
            acc1 += c0 * f0.y + c1 * f1.y + c2 * f2.y + c3 * f3.y
                  + c4 * f4.y + c5 * f5.y + c6 * f6.y + c7 * f7.y;
        }
        for (; j + 4 <= re; j += 4) {
            unsigned long long u0 = __builtin_nontemporal_load(ep + j);
            unsigned long long u1 = __builtin_nontemporal_load(ep + j + 1);
            unsigned long long u2 = __builtin_nontemporal_load(ep + j + 2);
            unsigned long long u3 = __builtin_nontemporal_load(ep + j + 3);
            unsigned v0 = xw[(size_t)(unsigned)u0 * 64 + lane];
            unsigned v1 = xw[(size_t)(unsigned)u1 * 64 + lane];
            unsigned v2 = xw[(size_t)(unsigned)u2 * 64 + lane];
            unsigned v3 = xw[(size_t)(unsigned)u3 * 64 + lane];
            float c0 = __int_as_float((int)(u0 >> 32)), c1 = __int_as_float((int)(u1 >> 32));
            float c2 = __int_as_float((int)(u2 >> 32)), c3 = __int_as_float((int)(u3 >> 32));
            float2 f0 = bf2_unpack(v0), f1 = bf2_unpack(v1);
            float2 f2 = bf2_unpack(v2), f3 = bf2_unpack(v3);
            acc0 += c0 * f0.x + c1 * f1.x + c2 * f2.x + c3 * f3.x;
            acc1 += c0 * f0.y + c1 * f1.y + c2 * f2.y + c3 * f3.y;
        }
        for (; j < re; j++) {
            unsigned long long u = __builtin_nontemporal_load(ep + j);
            float c = __int_as_float((int)(u >> 32));
            float2 f = bf2_unpack(xw[(size_t)(unsigned)u * 64 + lane]);
            acc0 += c * f.x;
            acc1 += c * f.y;
        }
        acc0 = acc0 * di + b0;
        acc1 = acc1 * di + b1;
        __builtin_nontemporal_store(bf2_pack(acc0, acc1), &h[(size_t)i * 64 + lane]);
        s0 += acc0; s1 += acc1; q0 += acc0 * acc0; q1 += acc1 * acc1;
    }

    redS[wave * 128 + 2 * lane] = s0;
    redS[wave * 128 + 2 * lane + 1] = s1;
    redQ[wave * 128 + 2 * lane] = q0;
    redQ[wave * 128 + 2 * lane + 1] = q1;
    __syncthreads();
    if (threadIdx.x < 128) {
        int f = threadIdx.x;
        float ts = redS[f] + redS[128 + f] + redS[256 + f] + redS[384 + f];
        float tq = redQ[f] + redQ[128 + f] + redQ[256 + f] + redQ[384 + f];
        atomicAdd(&bn_sum[f], ts);
        atomicAdd(&bn_sq[f], tq);
    }
}

// ---------- BN finalize ----------
__global__ void k_bnfin(const float* __restrict__ bn_sum, const float* __restrict__ bn_sq,
                        const float* __restrict__ gamma, const float* __restrict__ beta,
                        float* __restrict__ scale, float* __restrict__ shift, int N) {
    int f = threadIdx.x;
    float inv = 1.0f / (float)N;
    float m = bn_sum[f] * inv;
    float v = bn_sq[f] * inv - m * m;
    float sc = gamma[f] * rsqrtf(v + 1e-5f);
    scale[f] = sc;
    shift[f] = beta[f] - m * sc;
}

// ---------- aggregation (40-wide, bf16 gather) + bias + log_softmax ----------
__global__ __launch_bounds__(256) void k_agg40(
    const unsigned* __restrict__ xw, const int* __restrict__ rowptr,
    const unsigned long long* __restrict__ ep, const float* __restrict__ dinv,
    const float* __restrict__ bias, float* __restrict__ out, int N)
{
    const int lane = threadIdx.x & 63;
    const int wave = threadIdx.x >> 6;
    const int half = lane >> 5;
    const int col = lane & 31;
    const bool act = col < 20;
    const int base = blockIdx.x * 64 + wave * 16;
    if (base >= N) return;
    const int cc = act ? col : 0;
    const float b0 = act ? bias[2 * col] : 0.f;
    const float b1 = act ? bias[2 * col + 1] : 0.f;

    for (int n = 0; n < 16; n += 2) {
        const int i = base + n + half;
        const bool valid = i < N;
        const int ic = valid ? i : 0;
        const int rs = rowptr[ic];
        int re = rowptr[ic + 1];
        re = valid ? re : rs;
        const float di = dinv[ic];
        float2 sv = bf2_unpack(xw[(size_t)ic * 20 + cc]);
        float acc0 = sv.x, acc1 = sv.y;
        int j = rs;
        for (; j + 8 <= re; j += 8) {
            unsigned long long u0 = __builtin_nontemporal_load(ep + j);
            unsigned long long u1 = __builtin_nontemporal_load(ep + j + 1);
            unsigned long long u2 = __builtin_nontemporal_load(ep + j + 2);
            unsigned long long u3 = __builtin_nontemporal_load(ep + j + 3);
            unsigned long long u4 = __builtin_nontemporal_load(ep + j + 4);
            unsigned long long u5 = __builtin_nontemporal_load(ep + j + 5);
            unsigned long long u6 = __builtin_nontemporal_load(ep + j + 6);
            unsigned long long u7 = __builtin_nontemporal_load(ep + j + 7);
            unsigned v0 = xw[(size_t)(unsigned)u0 * 20 + cc];
            unsigned v1 = xw[(size_t)(unsigned)u1 * 20 + cc];
            unsigned v2 = xw[(size_t)(unsigned)u2 * 20 + cc];
            unsigned v3 = xw[(size_t)(unsigned)u3 * 20 + cc];
            unsigned v4 = xw[(size_t)(unsigned)u4 * 20 + cc];
            unsigned v5 = xw[(size_t)(unsigned)u5 * 20 + cc];
            unsigned v6 = xw[(size_t)(unsigned)u6 * 20 + cc];
            unsigned v7 = xw[(size_t)(unsigned)u7 * 20 + cc];
            float c0 = __int_as_float((int)(u0 >> 32)), c1 = __int_as_float((int)(u1 >> 32));
            float c2 = __int_as_float((int)(u2 >> 32)), c3 = __int_as_float((int)(u3 >> 32));
            float c4 = __int_as_float((int)(u4 >> 32)), c5 = __int_as_float((int)(u5 >> 32));
            float c6 = __int_as_float((int)(u6 >> 32)), c7 = __int_as_float((int)(u7 >> 32));
            float2 f0 = bf2_unpack(v0), f1 = bf2_unpack(v1);
            float2 f2 = bf2_unpack(v2), f3 = bf2_unpack(v3);
            float2 f4 = bf2_unpack(v4), f5 = bf2_unpack(v5);
            float2 f6 = bf2_unpack(v6), f7 = bf2_unpack(v7);
            acc0 += c0 * f0.x + c1 * f1.x + c2 * f2.x + c3 * f3.x
                  + c4 * f4.x + c5 * f5.x + c6 * f6.x + c7 * f7.x;
            acc1 += c0 * f0.y + c1 * f1.y + c2 * f2.y + c3 * f3.y
                  + c4 * f4.y + c5 * f5.y + c6 * f6.y + c7 * f7.y;
        }
        for (; j < re; j++) {
            unsigned long long u = __builtin_nontemporal_load(ep + j);
            float c = __int_as_float((int)(u >> 32));
            float2 f = bf2_unpack(xw[(size_t)(unsigned)u * 20 + cc]);
            acc0 += c * f.x;
            acc1 += c * f.y;
        }
        acc0 = acc0 * di + b0;
        acc1 = acc1 * di + b1;

        float m = act ? fmaxf(acc0, acc1) : -1e30f;
#pragma unroll
        for (int off = 16; off; off >>= 1) m = fmaxf(m, __shfl_xor(m, off));
        float ex = act ? (expf(acc0 - m) + expf(acc1 - m)) : 0.f;
#pragma unroll
        for (int off = 16; off; off >>= 1) ex += __shfl_xor(ex, off);
        float ls = logf(ex);
        if (act && valid)
            *(float2*)&out[(size_t)i * 40 + 2 * col] = make_float2(acc0 - m - ls, acc1 - m - ls);
    }
}

// ---------------------------------------------------------------------------
extern "C" void kernel_launch(void* const* d_in, const int* in_sizes, int n_in,
                              void* d_out, int out_size, void* d_ws, size_t ws_size,
                              hipStream_t stream) {
    const float* x   = (const float*)d_in[0];
    const unsigned* ei = (const unsigned*)d_in[1];
    const float* ew  = (const float*)d_in[2];
    const float* W0  = (const float*)d_in[3];
    const float* b0  = (const float*)d_in[4];
    const float* g0  = (const float*)d_in[5];
    const float* be0 = (const float*)d_in[6];
    const float* W1  = (const float*)d_in[7];
    const float* b1  = (const float*)d_in[8];
    const float* g1  = (const float*)d_in[9];
    const float* be1 = (const float*)d_in[10];
    const float* W2  = (const float*)d_in[11];
    const float* b2  = (const float*)d_in[12];

    const int N = in_sizes[0] / 128;
    const int E = in_sizes[2];
    if (N <= 0 || E <= 0) return;
    const int NB = (N + 255) >> 8;
    const int nchunks = (E + CHUNK - 1) / CHUNK;

    char* ws = (char*)d_ws;
    size_t off = 0;
    auto carve = [&](size_t bytes) {
        char* p = ws + off;
        off += (bytes + 511) & ~((size_t)511);
        return p;
    };
    unsigned* F       = (unsigned*)carve((size_t)N * 64 * 4);  // packed bf162 h
    unsigned* P       = (unsigned*)carve((size_t)N * 64 * 4);  // packed bf162 xw'
    int2*     ep      = (int2*)carve((size_t)E * 8);
    int2*     staging = (int2*)carve((size_t)E * 8);
    int*      chist   = (int*)carve((size_t)nchunks * 512 * 4);
    int*      rowptr  = (int*)carve((size_t)(N + 1) * 4);
    float*    dinv    = (float*)carve((size_t)N * 4);
    int*      bstart  = (int*)carve(513 * 4);
    int*      bcur    = (int*)carve(513 * 4);
    float*    bn      = (float*)carve(512 * 4);

    int pgrid = nchunks < 1024 ? nchunks : 1024;
    k_bhist<<<pgrid, 256, 0, stream>>>(ei, chist, E, NB, nchunks);
    k_bscan<<<1, 512, 0, stream>>>(chist, bstart, bcur, NB, nchunks);
    k_part<<<pgrid, 256, 0, stream>>>(ei, ew, chist, bcur, staging, E, NB, nchunks);
    k_bucket<<<NB, 256, 0, stream>>>(bstart, staging, rowptr, dinv, ep, N, NB);

    const int agg_grid = (N + 63) / 64;
    const unsigned long long* epu = (const unsigned long long*)ep;

    // ---- layer 0 ----
    k_gemm_mfma<128, 4, false, true><<<1024, 256, 0, stream>>>(x, nullptr, W0, nullptr, nullptr, dinv, P, bn, N);
    k_agg128<<<agg_grid, 256, 0, stream>>>(P, rowptr, epu, dinv, b0, F, bn, bn + 128, N);
    k_bnfin<<<1, 128, 0, stream>>>(bn, bn + 128, g0, be0, bn + 256, bn + 384, N);

    // ---- layer 1 ----
    k_gemm_mfma<128, 4, true, false><<<1024, 256, 0, stream>>>(nullptr, F, W1, bn + 256, bn + 384, dinv, P, bn, N);
    k_agg128<<<agg_grid, 256, 0, stream>>>(P, rowptr, epu, dinv, b1, F, bn, bn + 128, N);
    k_bnfin<<<1, 128, 0, stream>>>(bn, bn + 128, g1, be1, bn + 256, bn + 384, N);

    // ---- layer 2 ----
    k_gemm_mfma<40, 2, true, false><<<1024, 256, 0, stream>>>(nullptr, F, W2, bn + 256, bn + 384, dinv, P, nullptr, N);
    k_agg40<<<agg_grid, 256, 0, stream>>>(P, rowptr, epu, dinv, b2, (float*)d_out, N);
}